// Round 1
// baseline (165.720 us; speedup 1.0000x reference)
//
#include <hip/hip_runtime.h>

#define EPSF 1e-6f

// ---------------------------------------------------------------------------
// Kernel 1: zero the 66-accumulator-per-batch workspace (ws is poisoned 0xAA).
// ---------------------------------------------------------------------------
__global__ __launch_bounds__(256) void msl_zero(float* __restrict__ acc, int n) {
  int i = blockIdx.x * blockDim.x + threadIdx.x;
  if (i < n) acc[i] = 0.0f;
}

// ---------------------------------------------------------------------------
// Kernel 2: streaming reduction. For each batch b accumulate:
//   acc[b*66 + 0]           = sum pred[b,0,:] * gt[b,0,:]           (bg inter)
//   acc[b*66 + 1 + p*7 + g] = sum pred[b,p+1,:] * gt[b,g+1,:]       (fg inter)
//   acc[b*66 + 50 + s]      = sum pred[b,s,:]                       (pred sums)
//   acc[b*66 + 58 + s]      = sum gt[b,s,:]                         (gt sums)
// Memory-bound: 128 MB fp32 streamed once, float4 loads, 66 reg accumulators.
// ---------------------------------------------------------------------------
__global__ __launch_bounds__(256) void msl_accum(const float* __restrict__ pred,
                                                 const float* __restrict__ gt,
                                                 float* __restrict__ acc,
                                                 int HW, int HW4) {
  const int b = blockIdx.y;
  const size_t base = (size_t)b * 8 * (size_t)HW;
  const float* P = pred + base;
  const float* G = gt + base;

  float a_bg = 0.0f;
  float af[7][7];
  float sp[8], sg[8];
#pragma unroll
  for (int p = 0; p < 7; ++p)
#pragma unroll
    for (int g = 0; g < 7; ++g) af[p][g] = 0.0f;
#pragma unroll
  for (int s = 0; s < 8; ++s) { sp[s] = 0.0f; sg[s] = 0.0f; }

  const int stride = blockDim.x * gridDim.x;
  for (int i = blockIdx.x * blockDim.x + threadIdx.x; i < HW4; i += stride) {
    float4 pv[8], gv[8];
#pragma unroll
    for (int s = 0; s < 8; ++s)
      pv[s] = ((const float4*)(P + (size_t)s * HW))[i];
#pragma unroll
    for (int s = 0; s < 8; ++s)
      gv[s] = ((const float4*)(G + (size_t)s * HW))[i];

#pragma unroll
    for (int s = 0; s < 8; ++s) {
      sp[s] += (pv[s].x + pv[s].y) + (pv[s].z + pv[s].w);
      sg[s] += (gv[s].x + gv[s].y) + (gv[s].z + gv[s].w);
    }
    a_bg += pv[0].x * gv[0].x + pv[0].y * gv[0].y +
            pv[0].z * gv[0].z + pv[0].w * gv[0].w;
#pragma unroll
    for (int p = 0; p < 7; ++p)
#pragma unroll
      for (int g = 0; g < 7; ++g)
        af[p][g] += pv[p + 1].x * gv[g + 1].x + pv[p + 1].y * gv[g + 1].y +
                    pv[p + 1].z * gv[g + 1].z + pv[p + 1].w * gv[g + 1].w;
  }

  // Pack 66 partials, wave-shuffle reduce (width 64), LDS cross-wave, atomic.
  float v[66];
  v[0] = a_bg;
#pragma unroll
  for (int p = 0; p < 7; ++p)
#pragma unroll
    for (int g = 0; g < 7; ++g) v[1 + p * 7 + g] = af[p][g];
#pragma unroll
  for (int s = 0; s < 8; ++s) { v[50 + s] = sp[s]; v[58 + s] = sg[s]; }

#pragma unroll
  for (int k = 0; k < 66; ++k) {
    float x = v[k];
#pragma unroll
    for (int off = 32; off > 0; off >>= 1) x += __shfl_down(x, off, 64);
    v[k] = x;
  }

  __shared__ float red[4][66];
  const int wave = threadIdx.x >> 6;
  const int lane = threadIdx.x & 63;
  if (lane == 0) {
#pragma unroll
    for (int k = 0; k < 66; ++k) red[wave][k] = v[k];
  }
  __syncthreads();
  if (threadIdx.x < 66) {
    float s = red[0][threadIdx.x] + red[1][threadIdx.x] +
              red[2][threadIdx.x] + red[3][threadIdx.x];
    atomicAdd(&acc[b * 66 + threadIdx.x], s);
  }
}

// ---------------------------------------------------------------------------
// Kernel 3: finalize. One block, 32 lanes per batch.
// dice[p][g] = (2*inter + eps) / (sum_p + sum_g + eps)
// Optimal assignment of first n gt slots to distinct pred slots via bitmask
// DP over used-pred-row sets (the Hungarian optimum VALUE is all we need:
// fg_loss = 1 - (sum of matched dice)/(total matched count)).
// dp stride 130 / dice stride 52: odd-ish strides break LDS bank conflicts.
// ---------------------------------------------------------------------------
__global__ __launch_bounds__(1024) void msl_final(const float* __restrict__ acc,
                                                  const int* __restrict__ nobj,
                                                  float* __restrict__ out, int B) {
  __shared__ float dp[32][130];
  __shared__ float dice[32][52];
  __shared__ float r_bg[32];
  __shared__ float r_ds[32];
  __shared__ int   r_n[32];

  const int batch = threadIdx.x >> 5;
  const int lane  = threadIdx.x & 31;
  const bool act  = (batch < B);

  if (act) {
    const float* a = acc + batch * 66;
    for (int k = lane; k < 49; k += 32) {
      int p = k / 7, g = k % 7;
      dice[batch][k] = (2.0f * a[1 + k] + EPSF) / (a[51 + p] + a[59 + g] + EPSF);
    }
    if (lane == 0) {
      float u = a[50] + a[58];
      r_bg[batch] = 1.0f - (2.0f * a[0] + EPSF) / (u + EPSF);
      int n = nobj[batch];
      n = n < 0 ? 0 : (n > 7 ? 7 : n);
      r_n[batch] = n;
      r_ds[batch] = 0.0f;
      dp[batch][0] = 0.0f;
    }
  }
  __syncthreads();
  const int n = act ? r_n[batch] : 0;

  // DP layers: masks of popcount c depend only on layer c-1; lane-parallel.
  for (int c = 1; c <= 7; ++c) {
    if (act && c <= n) {
      for (int mask = lane; mask < 128; mask += 32) {
        if (__popc(mask) == c) {
          float best = -1e30f;
#pragma unroll
          for (int r = 0; r < 7; ++r) {
            if (mask & (1 << r)) {
              float cand = dp[batch][mask ^ (1 << r)] + dice[batch][r * 7 + (c - 1)];
              best = fmaxf(best, cand);
            }
          }
          dp[batch][mask] = best;
        }
      }
    }
    __syncthreads();
  }

  float best = -1e30f;
  if (act && n > 0) {
    for (int mask = lane; mask < 128; mask += 32)
      if (__popc(mask) == n) best = fmaxf(best, dp[batch][mask]);
  }
#pragma unroll
  for (int off = 16; off > 0; off >>= 1)
    best = fmaxf(best, __shfl_down(best, off, 32));
  if (act && lane == 0 && n > 0) r_ds[batch] = best;
  __syncthreads();

  if (threadIdx.x == 0) {
    float bg = 0.0f, ds = 0.0f;
    int cnt = 0;
    for (int b = 0; b < B; ++b) { bg += r_bg[b]; ds += r_ds[b]; cnt += r_n[b]; }
    float fg = cnt > 0 ? ((float)cnt - ds) / (float)cnt : 0.0f;
    out[0] = bg / (float)B + fg;
  }
}

// ---------------------------------------------------------------------------
extern "C" void kernel_launch(void* const* d_in, const int* in_sizes, int n_in,
                              void* d_out, int out_size, void* d_ws, size_t ws_size,
                              hipStream_t stream) {
  const float* pred = (const float*)d_in[0];
  const float* gt   = (const float*)d_in[1];
  const int*   nobj = (const int*)d_in[2];
  float* out = (float*)d_out;

  const int B  = in_sizes[2];              // 32
  const int HW = in_sizes[0] / (B * 8);    // 65536
  const int HW4 = HW / 4;

  float* acc = (float*)d_ws;               // B*66 floats
  const int accN = B * 66;

  msl_zero<<<dim3((accN + 255) / 256), dim3(256), 0, stream>>>(acc, accN);

  const int blocksPerBatch = 32;           // 1024 blocks total, 2 f4-iters/thread
  msl_accum<<<dim3(blocksPerBatch, B), dim3(256), 0, stream>>>(pred, gt, acc, HW, HW4);

  msl_final<<<dim3(1), dim3(32 * B), 0, stream>>>(acc, nobj, out, B);
}